// Round 2
// baseline (2916.610 us; speedup 1.0000x reference)
//
#include <hip/hip_runtime.h>
#include <stdint.h>

#define N_PIX 65536
#define HH 256
#define WW 256
#define KM 9

// ---- workspace layout (bytes) ----
#define WS_BITS  0u                               // uint32[65536]          256 KB
#define WS_CNT   262144u                          // int[16]
#define WS_CNT1  (262144u + 64u)                  // int[16]
#define WS_SUMS  (262144u + 128u)                 // float[9*256]
#define WS_MEANS (262144u + 128u + 9216u)         // float[9*256]
#define WS_C1    (1u<<20)                         // float[128*65536]  32 MB
#define WS_C2    (WS_C1 + 128u*65536u*4u)         // float[64*65536]   16 MB
#define WS_FV    (WS_C2 + 64u*65536u*4u)          // float[32*65536]    8 MB
#define WS_PART  (WS_FV + 32u*65536u*4u)          // float[256*9216]  9.4 MB
#define WS_COV   (WS_PART + 256u*9216u*4u)        // float[9*1024]

// ---------------- mask pack + counts ----------------
__global__ void k_pack(const int* __restrict__ masks, uint32_t* __restrict__ bits,
                       int* __restrict__ counts, int* __restrict__ cnt1) {
    int n = blockIdx.x * 256 + threadIdx.x;
    uint32_t fg = 0, f1 = 0;
#pragma unroll
    for (int k = 0; k < KM; ++k) {
        int m = masks[k * N_PIX + n];
        fg |= (uint32_t)(m > 0) << k;
        f1 |= (uint32_t)(m == 1) << k;
    }
    bits[n] = fg | (f1 << 16);
#pragma unroll
    for (int k = 0; k < KM; ++k) {
        unsigned long long b0 = __ballot((fg >> k) & 1);
        unsigned long long b1 = __ballot((f1 >> k) & 1);
        if ((threadIdx.x & 63) == 0) {
            atomicAdd(&counts[k], __popcll(b0));
            atomicAdd(&cnt1[k], __popcll(b1));
        }
    }
}

// ---------------- per-(mask,channel) sums ----------------
__global__ void k_sums(const float* __restrict__ x, const uint32_t* __restrict__ bits,
                       float* __restrict__ sums) {
    int c = blockIdx.x >> 4;
    int chunk = blockIdx.x & 15;
    int base = chunk * 4096;
    float acc[KM];
#pragma unroll
    for (int k = 0; k < KM; ++k) acc[k] = 0.0f;
    const float* xc = x + (size_t)c * N_PIX;
    for (int i = 0; i < 16; ++i) {
        int px = base + i * 256 + threadIdx.x;
        float xv = xc[px];
        uint32_t b = bits[px];
#pragma unroll
        for (int k = 0; k < KM; ++k) acc[k] += ((b >> k) & 1) ? xv : 0.0f;
    }
#pragma unroll
    for (int k = 0; k < KM; ++k) {
        float v = acc[k];
        for (int off = 32; off; off >>= 1) v += __shfl_down(v, off);
        if ((threadIdx.x & 63) == 0) atomicAdd(&sums[k * 256 + c], v);
    }
}

__global__ void k_means(const float* __restrict__ sums, const int* __restrict__ counts,
                        float* __restrict__ means) {
    int k = blockIdx.x, c = threadIdx.x;
    means[k * 256 + c] = sums[k * 256 + c] / fmaxf((float)counts[k], 1.0f);
}

// ---------------- fsm = x - mean[last valid covering mask] ----------------
__global__ void k_fsm(const float* __restrict__ x, const uint32_t* __restrict__ bits,
                      const int* __restrict__ counts, const float* __restrict__ means,
                      float* __restrict__ fsm) {
    __shared__ float mst[256 * 12];   // [c][k] transposed, padded stride 12
    int tid = threadIdx.x;
    for (int t = tid; t < KM * 256; t += 256) {
        int k = t >> 8, c = t & 255;
        mst[c * 12 + k] = means[t];
    }
    __syncthreads();
    uint32_t vm = 0;
#pragma unroll
    for (int k = 0; k < KM; ++k) vm |= (uint32_t)(counts[k] >= 10) << k;
    int px = blockIdx.x * 256 + tid;
    uint32_t sel = bits[px] & vm & 0x1FFu;
    int kl = 0; float have = 0.0f;
    if (sel) { kl = 31 - __clz((int)sel); have = 1.0f; }   // LAST valid mask wins
#pragma unroll 4
    for (int c = 0; c < 256; ++c) {
        float xv = x[(size_t)c * N_PIX + px];
        float sub = have * mst[c * 12 + kl];
        fsm[(size_t)c * N_PIX + px] = xv - sub;
    }
}

// ---------------- direct 3x3 conv, fp32, NCHW ----------------
template<int IC, int OCB, bool RELU>
__global__ __launch_bounds__(256) void k_conv(const float* __restrict__ in,
                                              const float* __restrict__ w,
                                              const float* __restrict__ bias,
                                              float* __restrict__ outp) {
    const int x = threadIdx.x;
    const int y = blockIdx.x;
    const int oc0 = blockIdx.y * OCB;
    float acc[OCB];
#pragma unroll
    for (int o = 0; o < OCB; ++o) acc[o] = bias[oc0 + o];
    const bool okxm = (x > 0), okxp = (x < WW - 1);
    const bool okym = (y > 0), okyp = (y < HH - 1);
    const float* wbase = w + (size_t)oc0 * IC * 9;
    for (int ic = 0; ic < IC; ++ic) {
        const float* r1 = in + (size_t)ic * N_PIX + y * WW + x;
        const float* r0 = r1 - WW;
        const float* r2 = r1 + WW;
        float t0 = (okym && okxm) ? r0[-1] : 0.0f;
        float t1 = okym ? r0[0] : 0.0f;
        float t2 = (okym && okxp) ? r0[1] : 0.0f;
        float t3 = okxm ? r1[-1] : 0.0f;
        float t4 = r1[0];
        float t5 = okxp ? r1[1] : 0.0f;
        float t6 = (okyp && okxm) ? r2[-1] : 0.0f;
        float t7 = okyp ? r2[0] : 0.0f;
        float t8 = (okyp && okxp) ? r2[1] : 0.0f;
        const float* wi = wbase + ic * 9;
#pragma unroll
        for (int o = 0; o < OCB; ++o) {
            const float* wo = wi + (size_t)o * IC * 9;   // uniform -> s_load path
            float s = fmaf(wo[0], t0, acc[o]);
            s = fmaf(wo[1], t1, s);
            s = fmaf(wo[2], t2, s);
            s = fmaf(wo[3], t3, s);
            s = fmaf(wo[4], t4, s);
            s = fmaf(wo[5], t5, s);
            s = fmaf(wo[6], t6, s);
            s = fmaf(wo[7], t7, s);
            acc[o] = fmaf(wo[8], t8, s);
        }
    }
#pragma unroll
    for (int o = 0; o < OCB; ++o) {
        float v = acc[o];
        if (RELU) v = fmaxf(v, 0.0f);
        outp[(size_t)(oc0 + o) * N_PIX + y * WW + x] = v;
    }
}

// ---------------- masked covariance partials ----------------
__global__ __launch_bounds__(256) void k_cov(const float* __restrict__ fv,
                                             const uint32_t* __restrict__ bits,
                                             float* __restrict__ part) {
    __shared__ float sf[32 * 257];   // [c][px] padded (257 % 32 == 1) -> conflict-free
    __shared__ uint32_t sb[256];
    int px0 = blockIdx.x * 256;
    int tid = threadIdx.x;
    for (int r = 0; r < 32; ++r) sf[r * 257 + tid] = fv[(size_t)r * N_PIX + px0 + tid];
    sb[tid] = bits[px0 + tid] >> 16;   // fg1 bits
    __syncthreads();
    int c = tid >> 3;            // 0..31
    int d4 = (tid & 7) * 4;      // 0,4,...,28
    float a[KM][4];
#pragma unroll
    for (int k = 0; k < KM; ++k)
#pragma unroll
        for (int j = 0; j < 4; ++j) a[k][j] = 0.0f;
#pragma unroll 2
    for (int px = 0; px < 256; ++px) {
        float fc = sf[c * 257 + px];
        float f0 = sf[(d4 + 0) * 257 + px];
        float f1 = sf[(d4 + 1) * 257 + px];
        float f2 = sf[(d4 + 2) * 257 + px];
        float f3 = sf[(d4 + 3) * 257 + px];
        uint32_t b = sb[px];
#pragma unroll
        for (int k = 0; k < KM; ++k) {
            float fm = ((b >> k) & 1) ? fc : 0.0f;
            a[k][0] = fmaf(fm, f0, a[k][0]);
            a[k][1] = fmaf(fm, f1, a[k][1]);
            a[k][2] = fmaf(fm, f2, a[k][2]);
            a[k][3] = fmaf(fm, f3, a[k][3]);
        }
    }
    float* po = part + (size_t)blockIdx.x * 9216 + (c * 32 + d4);
#pragma unroll
    for (int k = 0; k < KM; ++k)
#pragma unroll
        for (int j = 0; j < 4; ++j) po[k * 1024 + j] = a[k][j];
}

__global__ void k_covred(const float* __restrict__ part, float* __restrict__ cov) {
    int p = blockIdx.x * 256 + threadIdx.x;   // 0..9215
    float s = 0.0f;
    for (int b = 0; b < 256; ++b) s += part[(size_t)b * 9216 + p];
    cov[p] = s;
}

// ---------------- FC + validity ----------------
__global__ void k_fc(const float* __restrict__ cov, const int* __restrict__ cnt1,
                     const float* __restrict__ fcw, const float* __restrict__ fcb,
                     float* __restrict__ trans) {
    int k = blockIdx.x;
    int j = blockIdx.y * 256 + threadIdx.x;
    __shared__ float sc[1024];
    int c1 = cnt1[k];
    float inv = 1.0f / fmaxf((float)c1, 1.0f);
    for (int t = threadIdx.x; t < 1024; t += 256) sc[t] = cov[k * 1024 + t] * inv;
    __syncthreads();
    const float4* wrow = (const float4*)(fcw + (size_t)j * 1024);
    float acc = fcb[j];
#pragma unroll 4
    for (int i4 = 0; i4 < 256; ++i4) {
        float4 wv = wrow[i4];
        acc += sc[i4 * 4 + 0] * wv.x + sc[i4 * 4 + 1] * wv.y +
               sc[i4 * 4 + 2] * wv.z + sc[i4 * 4 + 3] * wv.w;
    }
    trans[k * 1024 + j] = (c1 >= 10) ? acc : 0.0f;
}

extern "C" void kernel_launch(void* const* d_in, const int* in_sizes, int n_in,
                              void* d_out, int out_size, void* d_ws, size_t ws_size,
                              hipStream_t stream) {
    const float* x     = (const float*)d_in[0];
    const int*   masks = (const int*)  d_in[1];
    const float* w1    = (const float*)d_in[2];
    const float* b1    = (const float*)d_in[3];
    const float* w2    = (const float*)d_in[4];
    const float* b2    = (const float*)d_in[5];
    const float* w3    = (const float*)d_in[6];
    const float* b3    = (const float*)d_in[7];
    const float* fcw   = (const float*)d_in[8];
    const float* fcb   = (const float*)d_in[9];

    float* out   = (float*)d_out;
    float* trans = out;                 // [9][1024]
    float* fsm   = out + KM * 1024;     // [256][65536]

    char* ws = (char*)d_ws;
    uint32_t* bits  = (uint32_t*)(ws + WS_BITS);
    int*   counts   = (int*)  (ws + WS_CNT);
    int*   cnt1     = (int*)  (ws + WS_CNT1);
    float* sums     = (float*)(ws + WS_SUMS);
    float* means    = (float*)(ws + WS_MEANS);
    float* c1buf    = (float*)(ws + WS_C1);
    float* c2buf    = (float*)(ws + WS_C2);
    float* fv       = (float*)(ws + WS_FV);
    float* part     = (float*)(ws + WS_PART);
    float* cov      = (float*)(ws + WS_COV);

    hipMemsetAsync(ws + WS_CNT, 0, 64 + 64 + 9216, stream);   // counts, cnt1, sums

    k_pack <<<256, 256, 0, stream>>>(masks, bits, counts, cnt1);
    k_sums <<<4096, 256, 0, stream>>>(x, bits, sums);
    k_means<<<KM, 256, 0, stream>>>(sums, counts, means);
    k_fsm  <<<256, 256, 0, stream>>>(x, bits, counts, means, fsm);

    k_conv<256, 64, true ><<<dim3(256, 2), 256, 0, stream>>>(fsm,   w1, b1, c1buf);
    k_conv<128, 32, true ><<<dim3(256, 2), 256, 0, stream>>>(c1buf, w2, b2, c2buf);
    k_conv< 64, 16, false><<<dim3(256, 2), 256, 0, stream>>>(c2buf, w3, b3, fv);

    k_cov   <<<256, 256, 0, stream>>>(fv, bits, part);
    k_covred<<<36, 256, 0, stream>>>(part, cov);
    k_fc    <<<dim3(KM, 4), 256, 0, stream>>>(cov, cnt1, fcw, fcb, trans);
}

// Round 3
// 654.948 us; speedup vs baseline: 4.4532x; 4.4532x over previous
//
#include <hip/hip_runtime.h>
#include <stdint.h>

#define N_PIX 65536
#define KM 9

typedef __bf16  bf16x8 __attribute__((ext_vector_type(8)));
typedef float   f32x4  __attribute__((ext_vector_type(4)));

__device__ __forceinline__ unsigned short f2bf(float f) {
    uint32_t u = __builtin_bit_cast(uint32_t, f);
    uint32_t r = (u + 0x7FFFu + ((u >> 16) & 1u)) >> 16;
    return (unsigned short)r;
}

// ---- workspace layout (bytes) ----
#define WS_BITS  0u              // uint32[65536]  256KB
#define WS_CNT   262144u         // int[16]
#define WS_CNT1  262208u         // int[16]
#define WS_SUMS  262272u         // float[9*256]
#define WS_MEANS 271488u         // float[9*256]
#define WS_W1T   282624u         // ushort 9*128*256 = 589824 B
#define WS_W2T   872448u         // ushort 9*64*128  = 147456 B
#define WS_W3T   1019904u        // ushort 9*32*64   = 36864 B
#define WS_COV   1056768u        // float[9*1024]    36864 B
#define WS_XB    2097152u        // ushort[65536*256] = 33.55 MB   [fsm->conv1]
#define WS_FV    2097152u        // float[65536*32] = 8.39 MB  (overlaps XB; conv3->cov)
#define WS_PART  14680064u       // float[256*9216] = 9.44 MB  (overlaps XB; cov->covred)
#define WS_C1B   35651584u       // ushort[65536*128] = 16.78 MB
#define WS_C2B   52428800u       // ushort[65536*64]  = 8.39 MB

// ---------------- mask pack + counts ----------------
__global__ void k_pack(const int* __restrict__ masks, uint32_t* __restrict__ bits,
                       int* __restrict__ counts, int* __restrict__ cnt1) {
    int n = blockIdx.x * 256 + threadIdx.x;
    uint32_t fg = 0, f1 = 0;
#pragma unroll
    for (int k = 0; k < KM; ++k) {
        int m = masks[k * N_PIX + n];
        fg |= (uint32_t)(m > 0) << k;
        f1 |= (uint32_t)(m == 1) << k;
    }
    bits[n] = fg | (f1 << 16);
#pragma unroll
    for (int k = 0; k < KM; ++k) {
        unsigned long long b0 = __ballot((fg >> k) & 1);
        unsigned long long b1 = __ballot((f1 >> k) & 1);
        if ((threadIdx.x & 63) == 0) {
            atomicAdd(&counts[k], __popcll(b0));
            atomicAdd(&cnt1[k], __popcll(b1));
        }
    }
}

// ---------------- per-(mask,channel) sums ----------------
__global__ void k_sums(const float* __restrict__ x, const uint32_t* __restrict__ bits,
                       float* __restrict__ sums) {
    int c = blockIdx.x >> 4;
    int base = (blockIdx.x & 15) * 4096;
    float acc[KM];
#pragma unroll
    for (int k = 0; k < KM; ++k) acc[k] = 0.0f;
    const float* xc = x + (size_t)c * N_PIX;
    for (int i = 0; i < 16; ++i) {
        int px = base + i * 256 + threadIdx.x;
        float xv = xc[px];
        uint32_t b = bits[px];
#pragma unroll
        for (int k = 0; k < KM; ++k) acc[k] += ((b >> k) & 1) ? xv : 0.0f;
    }
#pragma unroll
    for (int k = 0; k < KM; ++k) {
        float v = acc[k];
        for (int off = 32; off; off >>= 1) v += __shfl_down(v, off);
        if ((threadIdx.x & 63) == 0) atomicAdd(&sums[k * 256 + c], v);
    }
}

__global__ void k_means(const float* __restrict__ sums, const int* __restrict__ counts,
                        float* __restrict__ means) {
    int k = blockIdx.x, c = threadIdx.x;
    means[k * 256 + c] = sums[k * 256 + c] / fmaxf((float)counts[k], 1.0f);
}

// ---------------- fsm (fp32 NCHW out) + bf16 NHWC copy ----------------
__global__ void k_fsm(const float* __restrict__ x, const uint32_t* __restrict__ bits,
                      const int* __restrict__ counts, const float* __restrict__ means,
                      float* __restrict__ fsm, unsigned short* __restrict__ xb) {
    __shared__ float mst[256 * 12];
    int tid = threadIdx.x;
    for (int t = tid; t < KM * 256; t += 256) {
        int k = t >> 8, c = t & 255;
        mst[c * 12 + k] = means[t];
    }
    __syncthreads();
    uint32_t vm = 0;
#pragma unroll
    for (int k = 0; k < KM; ++k) vm |= (uint32_t)(counts[k] >= 10) << k;
    int px = blockIdx.x * 256 + tid;
    int c0 = blockIdx.y * 128;
    uint32_t sel = bits[px] & vm & 0x1FFu;
    int kl = 0; float have = 0.0f;
    if (sel) { kl = 31 - __clz((int)sel); have = 1.0f; }
    for (int cb = 0; cb < 128; cb += 8) {
        int c = c0 + cb;
        uint32_t pk[4];
#pragma unroll
        for (int j = 0; j < 8; j += 2) {
            float v0 = x[(size_t)(c + j) * N_PIX + px]     - have * mst[(c + j) * 12 + kl];
            float v1 = x[(size_t)(c + j + 1) * N_PIX + px] - have * mst[(c + j + 1) * 12 + kl];
            fsm[(size_t)(c + j) * N_PIX + px] = v0;
            fsm[(size_t)(c + j + 1) * N_PIX + px] = v1;
            pk[j >> 1] = (uint32_t)f2bf(v0) | ((uint32_t)f2bf(v1) << 16);
        }
        uint4 w; w.x = pk[0]; w.y = pk[1]; w.z = pk[2]; w.w = pk[3];
        *(uint4*)&xb[(size_t)px * 256 + c] = w;
    }
}

// ---------------- weight pack: OIHW fp32 -> [tap][oc][ic] bf16 ----------------
__global__ void k_wpack(const float* __restrict__ w, unsigned short* __restrict__ wt,
                        int total, int OC, int IC) {
    int idx = blockIdx.x * 256 + threadIdx.x;   // oc*IC + ic
    if (idx >= total) return;
    int oc = idx / IC, ic = idx - oc * IC;
    const float* src = w + (size_t)idx * 9;
#pragma unroll
    for (int t = 0; t < 9; ++t)
        wt[((size_t)t * OC + oc) * IC + ic] = f2bf(src[t]);
}

// ---------------- MFMA implicit-GEMM 3x3 conv, NHWC bf16 ----------------
// tile: 128 px (half row) x OC; 4 waves, each 32 px (2 M-tiles) x OC (NT N-tiles)
template<int IC, int OC, bool RELU, bool F32OUT>
__global__ __launch_bounds__(256) void k_convm(const unsigned short* __restrict__ xin,
                                               const unsigned short* __restrict__ wt,
                                               const float* __restrict__ bias,
                                               unsigned short* __restrict__ ybf,
                                               float* __restrict__ yf) {
    constexpr int NT = OC / 16;
    constexpr int NC = IC / 32;
    __shared__ unsigned short xs[4 * 3 * 130 * 8];   // [icg][row][px][8ic] 24960 B
    const int tid  = threadIdx.x;
    const int lane = tid & 63;
    const int wv   = tid >> 6;
    const int lo   = lane & 15;
    const int kg   = lane >> 4;
    const int y0   = blockIdx.x >> 1;
    const int x0   = (blockIdx.x & 1) << 7;

    f32x4 acc[2][NT];
#pragma unroll
    for (int m = 0; m < 2; ++m)
#pragma unroll
        for (int n = 0; n < NT; ++n) acc[m][n] = (f32x4){0.f, 0.f, 0.f, 0.f};
    float bs[NT];
#pragma unroll
    for (int n = 0; n < NT; ++n) bs[n] = bias[n * 16 + lo];

    for (int icc = 0; icc < NC; ++icc) {
        if (icc) __syncthreads();
        for (int u = tid; u < 1560; u += 256) {        // [row][px][icg] 16B units
            int row = u / 520;
            int r2  = u - row * 520;
            int px  = r2 >> 2;
            int icg = r2 & 3;
            int gy = y0 + row - 1;
            int gx = x0 + px - 1;
            uint4 v = make_uint4(0u, 0u, 0u, 0u);
            if ((unsigned)gy < 256u && (unsigned)gx < 256u)
                v = *(const uint4*)(xin + ((size_t)(gy * 256 + gx)) * IC + icc * 32 + icg * 8);
            *(uint4*)(xs + ((icg * 3 + row) * 130 + px) * 8) = v;
        }
        __syncthreads();
        const int abase = (kg * 3 * 130 + wv * 32 + lo) * 8;
#pragma unroll
        for (int tap = 0; tap < 9; ++tap) {
            const int tr = tap / 3, tc = tap % 3;
            bf16x8 wfrag[NT];
#pragma unroll
            for (int n = 0; n < NT; ++n)
                wfrag[n] = __builtin_bit_cast(bf16x8,
                    *(const uint4*)(wt + ((size_t)tap * OC + n * 16 + lo) * IC + icc * 32 + kg * 8));
            bf16x8 a0 = __builtin_bit_cast(bf16x8, *(const uint4*)(xs + abase + (tr * 130 + tc) * 8));
            bf16x8 a1 = __builtin_bit_cast(bf16x8, *(const uint4*)(xs + abase + (tr * 130 + tc) * 8 + 128));
#pragma unroll
            for (int n = 0; n < NT; ++n) {
                acc[0][n] = __builtin_amdgcn_mfma_f32_16x16x32_bf16(a0, wfrag[n], acc[0][n], 0, 0, 0);
                acc[1][n] = __builtin_amdgcn_mfma_f32_16x16x32_bf16(a1, wfrag[n], acc[1][n], 0, 0, 0);
            }
        }
    }
#pragma unroll
    for (int m = 0; m < 2; ++m) {
        int pxl = wv * 32 + m * 16 + kg * 4;
#pragma unroll
        for (int n = 0; n < NT; ++n) {
            int oc = n * 16 + lo;
#pragma unroll
            for (int r = 0; r < 4; ++r) {
                float v = acc[m][n][r] + bs[n];
                if (RELU) v = fmaxf(v, 0.0f);
                size_t px = (size_t)(y0 * 256 + x0 + pxl + r);
                if (F32OUT) yf[px * OC + oc] = v;
                else        ybf[px * OC + oc] = f2bf(v);
            }
        }
    }
}

// ---------------- masked covariance partials (fv = NHWC fp32 [px][32]) ----------------
__global__ __launch_bounds__(256) void k_cov(const float* __restrict__ fv,
                                             const uint32_t* __restrict__ bits,
                                             float* __restrict__ part) {
    __shared__ float sf[32 * 257];
    __shared__ uint32_t sb[256];
    int px0 = blockIdx.x * 256;
    int tid = threadIdx.x;
    const float4* src = (const float4*)(fv + (size_t)(px0 + tid) * 32);
#pragma unroll
    for (int q = 0; q < 8; ++q) {
        float4 v = src[q];
        sf[(q * 4 + 0) * 257 + tid] = v.x;
        sf[(q * 4 + 1) * 257 + tid] = v.y;
        sf[(q * 4 + 2) * 257 + tid] = v.z;
        sf[(q * 4 + 3) * 257 + tid] = v.w;
    }
    sb[tid] = bits[px0 + tid] >> 16;
    __syncthreads();
    int c = tid >> 3;
    int d4 = (tid & 7) * 4;
    float a[KM][4];
#pragma unroll
    for (int k = 0; k < KM; ++k)
#pragma unroll
        for (int j = 0; j < 4; ++j) a[k][j] = 0.0f;
#pragma unroll 2
    for (int px = 0; px < 256; ++px) {
        float fc = sf[c * 257 + px];
        float f0 = sf[(d4 + 0) * 257 + px];
        float f1 = sf[(d4 + 1) * 257 + px];
        float f2 = sf[(d4 + 2) * 257 + px];
        float f3 = sf[(d4 + 3) * 257 + px];
        uint32_t b = sb[px];
#pragma unroll
        for (int k = 0; k < KM; ++k) {
            float fm = ((b >> k) & 1) ? fc : 0.0f;
            a[k][0] = fmaf(fm, f0, a[k][0]);
            a[k][1] = fmaf(fm, f1, a[k][1]);
            a[k][2] = fmaf(fm, f2, a[k][2]);
            a[k][3] = fmaf(fm, f3, a[k][3]);
        }
    }
    float* po = part + (size_t)blockIdx.x * 9216 + (c * 32 + d4);
#pragma unroll
    for (int k = 0; k < KM; ++k)
#pragma unroll
        for (int j = 0; j < 4; ++j) po[k * 1024 + j] = a[k][j];
}

__global__ void k_covred(const float* __restrict__ part, float* __restrict__ cov) {
    int p = blockIdx.x * 256 + threadIdx.x;
    float s = 0.0f;
    for (int b = 0; b < 256; ++b) s += part[(size_t)b * 9216 + p];
    cov[p] = s;
}

// ---------------- FC + validity ----------------
__global__ void k_fc(const float* __restrict__ cov, const int* __restrict__ cnt1,
                     const float* __restrict__ fcw, const float* __restrict__ fcb,
                     float* __restrict__ trans) {
    int k = blockIdx.x;
    int j = blockIdx.y * 256 + threadIdx.x;
    __shared__ float sc[1024];
    int c1 = cnt1[k];
    float inv = 1.0f / fmaxf((float)c1, 1.0f);
    for (int t = threadIdx.x; t < 1024; t += 256) sc[t] = cov[k * 1024 + t] * inv;
    __syncthreads();
    const float4* wrow = (const float4*)(fcw + (size_t)j * 1024);
    float acc = fcb[j];
#pragma unroll 4
    for (int i4 = 0; i4 < 256; ++i4) {
        float4 wv = wrow[i4];
        acc += sc[i4 * 4 + 0] * wv.x + sc[i4 * 4 + 1] * wv.y +
               sc[i4 * 4 + 2] * wv.z + sc[i4 * 4 + 3] * wv.w;
    }
    trans[k * 1024 + j] = (c1 >= 10) ? acc : 0.0f;
}

extern "C" void kernel_launch(void* const* d_in, const int* in_sizes, int n_in,
                              void* d_out, int out_size, void* d_ws, size_t ws_size,
                              hipStream_t stream) {
    const float* x     = (const float*)d_in[0];
    const int*   masks = (const int*)  d_in[1];
    const float* w1    = (const float*)d_in[2];
    const float* b1    = (const float*)d_in[3];
    const float* w2    = (const float*)d_in[4];
    const float* b2    = (const float*)d_in[5];
    const float* w3    = (const float*)d_in[6];
    const float* b3    = (const float*)d_in[7];
    const float* fcw   = (const float*)d_in[8];
    const float* fcb   = (const float*)d_in[9];

    float* out   = (float*)d_out;
    float* trans = out;                 // [9][1024]
    float* fsm   = out + KM * 1024;     // [256][65536] fp32 NCHW

    char* ws = (char*)d_ws;
    uint32_t* bits = (uint32_t*)(ws + WS_BITS);
    int*   counts  = (int*)  (ws + WS_CNT);
    int*   cnt1    = (int*)  (ws + WS_CNT1);
    float* sums    = (float*)(ws + WS_SUMS);
    float* means   = (float*)(ws + WS_MEANS);
    unsigned short* w1t = (unsigned short*)(ws + WS_W1T);
    unsigned short* w2t = (unsigned short*)(ws + WS_W2T);
    unsigned short* w3t = (unsigned short*)(ws + WS_W3T);
    float* cov     = (float*)(ws + WS_COV);
    unsigned short* xb  = (unsigned short*)(ws + WS_XB);
    float* fv      = (float*)(ws + WS_FV);
    float* part    = (float*)(ws + WS_PART);
    unsigned short* c1b = (unsigned short*)(ws + WS_C1B);
    unsigned short* c2b = (unsigned short*)(ws + WS_C2B);

    hipMemsetAsync(ws + WS_CNT, 0, 64 + 64 + 9216, stream);

    k_wpack<<<128, 256, 0, stream>>>(w1, w1t, 128 * 256, 128, 256);
    k_wpack<<< 32, 256, 0, stream>>>(w2, w2t,  64 * 128,  64, 128);
    k_wpack<<<  8, 256, 0, stream>>>(w3, w3t,  32 *  64,  32,  64);

    k_pack <<<256, 256, 0, stream>>>(masks, bits, counts, cnt1);
    k_sums <<<4096, 256, 0, stream>>>(x, bits, sums);
    k_means<<<KM, 256, 0, stream>>>(sums, counts, means);
    k_fsm  <<<dim3(256, 2), 256, 0, stream>>>(x, bits, counts, means, fsm, xb);

    k_convm<256, 128, true,  false><<<512, 256, 0, stream>>>(xb,  w1t, b1, c1b, nullptr);
    k_convm<128,  64, true,  false><<<512, 256, 0, stream>>>(c1b, w2t, b2, c2b, nullptr);
    k_convm< 64,  32, false, true ><<<512, 256, 0, stream>>>(c2b, w3t, b3, nullptr, fv);

    k_cov   <<<256, 256, 0, stream>>>(fv, bits, part);
    k_covred<<<36, 256, 0, stream>>>(part, cov);
    k_fc    <<<dim3(KM, 4), 256, 0, stream>>>(cov, cnt1, fcw, fcb, trans);
}